// Round 4
// baseline (1696.102 us; speedup 1.0000x reference)
//
#include <hip/hip_runtime.h>

#define T_STEPS 1000
#define NB 256
#define DZ 64
#define DH 256
#define DS 16
#define CHUNK 64
#define NCHUNK 16   // 16*64 = 1024 intervals >= 1001 needed (store lags one step)

// LDS-only barrier: drains lgkmcnt (covers ds_read/ds_write/ds_add) but NOT vmcnt.
__device__ __forceinline__ void barrier_lgkm() {
    asm volatile("s_waitcnt lgkmcnt(0)\n\ts_barrier" ::: "memory");
}

// VALU-pipe cross-lane add via DPP. 0xB1 = quad_perm[1,0,3,2] (xor1);
// 0x4E = quad_perm[2,3,0,1] (xor2). Butterfly over a quad -> all 4 lanes hold sum.
template<int CTRL>
__device__ __forceinline__ float dpp_add(float x) {
    int y = __builtin_amdgcn_update_dpp(0, __float_as_int(x), CTRL, 0xF, 0xF, true);
    return x + __int_as_float(y);
}
__device__ __forceinline__ float rdlane(float v, int lane) {
    return __int_as_float(__builtin_amdgcn_readlane(__float_as_int(v), lane));
}

// ONE-BARRIER-PER-STEP schedule (round-9/10; round-8 showed the kernel is
// barrier/latency-bound, not issue-bound):
//  - wave w owns h in [16w,16w+16): quad k computes za[16w+k] in registers
//    (16 FMA + quad butterfly + med3) -- za never touches LDS.
//  - 16 v_readlane broadcast the wave's za to all lanes (SGPR-uniform).
//  - lane j of wave w computes its PARTIAL of z_new[j]: sum_k W2[j,16w+k]*za_k
//    + C[j,w]*s_t[w]  (the 16 waves exactly cover the DS=16 s-components),
//    then ds_add_f32-accumulates into the next z buffer.
//  - wave 1 folds A[j]*z_t[j]+h2[j] into its partial and stores z_t to out
//    (store lags one interval). wave 2 zeroes the 3rd buffer.
//  - 3 z-buffers rotate: read bc (complete), accumulate bn (pre-zeroed last
//    step), zero bo (last read 2 barriers ago -> race-free). ONE barrier/step.
//  - s staged in REGISTERS: lane l of wave w holds s[t0+l][b][w]; per step one
//    uniform v_readlane(sreg, tt). No s LDS traffic at all.
// ROUND-10 FIX: phase-1 z read was mis-paired (z4 = base + q with strided
// reads gave lane q the interleaved slice {4q, 16+4q, 32+4q, 48+4q} while w1v
// holds the contiguous slice [16q,16q+16)). Now z4 = base + 4q, consecutive
// z4[0..3] -- contiguous, matching w1v. Everything else unchanged.
__global__ __launch_bounds__(1024)
__attribute__((amdgpu_waves_per_eu(4, 4)))
void plrnn_scan(const float* __restrict__ z0, const float* __restrict__ s,
                const float* __restrict__ A,  const float* __restrict__ W1,
                const float* __restrict__ W2, const float* __restrict__ h1,
                const float* __restrict__ h2, const float* __restrict__ C,
                float* __restrict__ out)
{
    const int tid = threadIdx.x;
    const int b   = blockIdx.x;
    const int w   = tid >> 6;            // wave 0..15, owns h-block [16w,16w+16)
    const int l   = tid & 63;            // lane; also the output index j
    const int q   = l & 3;               // quad lane: covers z[16q..16q+16)
    const int k   = l >> 2;              // quad index: h = 16w + k
    const int h   = (w << 4) | k;

    __shared__ __align__(16) float zbuf[3][DZ];

    // ---- loop-invariant weights ----
    float4 w1v[4];    // W1[h][16q .. +16)
    {
        const float4* p = (const float4*)(W1 + (size_t)b * DH * DZ + (size_t)h * DZ + 16 * q);
        #pragma unroll
        for (int i = 0; i < 4; ++i) w1v[i] = p[i];
    }
    float4 w2v[4];    // W2[j=l][16w .. +16)
    {
        const float4* p = (const float4*)(W2 + (size_t)b * DZ * DH + (size_t)l * DH + 16 * w);
        #pragma unroll
        for (int i = 0; i < 4; ++i) w2v[i] = p[i];
    }
    const float cw = C[(l << 4) | w];     // C[j][w]: this wave's s-component

    // med3-relu constants: za = med3(sgn*p + off, lo, hi)
    const float h1r  = h1[h];
    const float rsgn = (h1r > 0.f) ?  1.f : -1.f;
    const float roff = (h1r > 0.f) ?  h1r :  0.f;
    const float rlo  = fminf(h1r, 0.f);
    const float rhi  = fmaxf(h1r, 0.f);

    const float Aj  = A[l];               // used by wave 1 only
    const float h2j = h2[l];

    if (tid < DZ) {
        zbuf[0][tid] = z0[b * DZ + tid];
        zbuf[1][tid] = 0.f;
        zbuf[2][tid] = 0.f;
    }

    // s prefetch into registers: lane l of wave w holds s[t0+l][b][w]
    const size_t sbase = (size_t)b * DS + w;
    float sregA = s[(size_t)min(l, T_STEPS - 1) * (NB * DS) + sbase];
    float sregB;

    float* bc = &zbuf[0][0];   // current z (read)
    float* bn = &zbuf[1][0];   // next z (ds_add accumulate; pre-zeroed)
    float* bo = &zbuf[2][0];   // old buffer (zero this interval)

    __syncthreads();

    for (int ci = 0; ci < NCHUNK; ++ci) {
        const int t0 = ci * CHUNK;
        {   // prefetch next chunk's s slice
            int tl = min(t0 + CHUNK + l, T_STEPS - 1);
            sregB = s[(size_t)tl * (NB * DS) + sbase];
        }

        #pragma unroll 4
        for (int tt = 0; tt < CHUNK; ++tt) {
            const int g = t0 + tt;       // interval index: consumes z_g, makes z_{g+1}

            // ---- phase 1 (intra-wave): za[16w+k] from full z ----
            const float4* z4 = (const float4*)bc + 4 * q;   // z[16q..16q+16), contiguous
            float4 zv0 = z4[0], zv1 = z4[1], zv2 = z4[2], zv3 = z4[3];
            float a0 = 0.f, a1 = 0.f, a2 = 0.f, a3 = 0.f;
            a0 = fmaf(w1v[0].x, zv0.x, a0); a1 = fmaf(w1v[0].y, zv0.y, a1);
            a2 = fmaf(w1v[0].z, zv0.z, a2); a3 = fmaf(w1v[0].w, zv0.w, a3);
            a0 = fmaf(w1v[1].x, zv1.x, a0); a1 = fmaf(w1v[1].y, zv1.y, a1);
            a2 = fmaf(w1v[1].z, zv1.z, a2); a3 = fmaf(w1v[1].w, zv1.w, a3);
            a0 = fmaf(w1v[2].x, zv2.x, a0); a1 = fmaf(w1v[2].y, zv2.y, a1);
            a2 = fmaf(w1v[2].z, zv2.z, a2); a3 = fmaf(w1v[2].w, zv2.w, a3);
            a0 = fmaf(w1v[3].x, zv3.x, a0); a1 = fmaf(w1v[3].y, zv3.y, a1);
            a2 = fmaf(w1v[3].z, zv3.z, a2); a3 = fmaf(w1v[3].w, zv3.w, a3);
            float p1 = (a0 + a1) + (a2 + a3);
            p1 = dpp_add<0xB1>(p1);      // quad butterfly xor1
            p1 = dpp_add<0x4E>(p1);      // quad butterfly xor2 -> all 4 lanes hold dot
            float za = __builtin_amdgcn_fmed3f(fmaf(rsgn, p1, roff), rlo, rhi);

            // ---- wave-wide za broadcast via readlane (za_k lives in lane 4k) ----
            // ---- phase 2 (intra-wave partial): sum_k W2[j,16w+k]*za_k + C[j,w]*s ----
            float sv = rdlane(sregA, tt);                 // s_t[b][w], uniform
            float p00 = fmaf(cw, sv, 0.f), p01 = 0.f, p02 = 0.f, p03 = 0.f;
            p00 = fmaf(w2v[0].x, rdlane(za,  0), p00);
            p01 = fmaf(w2v[0].y, rdlane(za,  4), p01);
            p02 = fmaf(w2v[0].z, rdlane(za,  8), p02);
            p03 = fmaf(w2v[0].w, rdlane(za, 12), p03);
            p00 = fmaf(w2v[1].x, rdlane(za, 16), p00);
            p01 = fmaf(w2v[1].y, rdlane(za, 20), p01);
            p02 = fmaf(w2v[1].z, rdlane(za, 24), p02);
            p03 = fmaf(w2v[1].w, rdlane(za, 28), p03);
            p00 = fmaf(w2v[2].x, rdlane(za, 32), p00);
            p01 = fmaf(w2v[2].y, rdlane(za, 36), p01);
            p02 = fmaf(w2v[2].z, rdlane(za, 40), p02);
            p03 = fmaf(w2v[2].w, rdlane(za, 44), p03);
            p00 = fmaf(w2v[3].x, rdlane(za, 48), p00);
            p01 = fmaf(w2v[3].y, rdlane(za, 52), p01);
            p02 = fmaf(w2v[3].z, rdlane(za, 56), p02);
            p03 = fmaf(w2v[3].w, rdlane(za, 60), p03);

            float zj = 0.f;
            if (w == 1) {                 // fold linear recurrence term + out store
                zj = bc[l];               // z_g[j]
                p00 = fmaf(Aj, zj, p00) + h2j;
            }
            float acc = (p00 + p01) + (p02 + p03);
            __hip_atomic_fetch_add(&bn[l], acc, __ATOMIC_RELAXED,
                                   __HIP_MEMORY_SCOPE_WORKGROUP);
            if (w == 2) bo[l] = 0.f;      // zero for interval g+1's accumulation
            if (w == 1 && g >= 1 && g <= T_STEPS)
                out[(size_t)(g - 1) * (NB * DZ) + b * DZ + l] = zj;

            // rotate buffers: next reads bn, accumulates bo(zeroed), zeroes bc
            float* tmp = bc; bc = bn; bn = bo; bo = tmp;
            barrier_lgkm();               // the ONE barrier per step
        }
        sregA = sregB;
    }
}

extern "C" void kernel_launch(void* const* d_in, const int* in_sizes, int n_in,
                              void* d_out, int out_size, void* d_ws, size_t ws_size,
                              hipStream_t stream) {
    const float* z0p = (const float*)d_in[0];
    const float* sp  = (const float*)d_in[1];
    const float* Ap  = (const float*)d_in[2];
    const float* W1p = (const float*)d_in[3];
    const float* W2p = (const float*)d_in[4];
    const float* h1p = (const float*)d_in[5];
    const float* h2p = (const float*)d_in[6];
    const float* Cp  = (const float*)d_in[7];

    plrnn_scan<<<dim3(NB), dim3(1024), 0, stream>>>(z0p, sp, Ap, W1p, W2p, h1p, h2p, Cp,
                                                    (float*)d_out);
}

// Round 5
// 583.822 us; speedup vs baseline: 2.9052x; 2.9052x over previous
//
#include <hip/hip_runtime.h>

#define T_STEPS 1000
#define NB 256
#define DZ 64
#define DH 256
#define DS 16
#define CHUNK 64
#define NCHUNK 16   // 16*64 = 1024 >= 1000; trailing 24 steps computed, unstored

// LDS-only barrier: drains lgkmcnt (LDS ordering) but NOT vmcnt.
// Safe: global loads land in private regs; global stores are never read back.
__device__ __forceinline__ void barrier_lgkm() {
    asm volatile("s_waitcnt lgkmcnt(0)\n\ts_barrier" ::: "memory");
}

// VALU-pipe cross-lane add via DPP (fuses to v_add_f32_dpp).
// CTRL: 0xB1 = quad_perm[1,0,3,2] (xor1); 0x4E = quad_perm[2,3,0,1] (xor2);
//       0x121/0x122/0x124/0x128 = row_ror 1/2/4/8.
template<int CTRL>
__device__ __forceinline__ float dpp_add(float x) {
    int y = __builtin_amdgcn_update_dpp(0, __float_as_int(x), CTRL, 0xF, 0xF, true);
    return x + __int_as_float(y);
}
// Sum across the 16 lanes of a DPP row (every lane ends with the row total).
__device__ __forceinline__ float row16_allsum(float x) {
    x = dpp_add<0x128>(x);   // += ror8
    x = dpp_add<0x124>(x);   // += ror4
    x = dpp_add<0x122>(x);   // += ror2
    x = dpp_add<0x121>(x);   // += ror1
    return x;
}

// One block per trial b; 1024 threads = 16 waves = 4 waves/SIMD.
// Round-11: EXACT round-1 structure (best measured: 557us rocprof / 593us bench).
// Round-4 proved the one-barrier atomic scheme is 3x worse (LDS same-address
// RMW serialization); round-2 proved bundled micro-changes regress via store
// placement. This round: round-1 + ONLY two pure-VALU trims, all else identical:
//  - relu(p+h1)-relu(p) as one v_med3_f32: h>=0 -> med3(p+h,0,h) via
//    (sgn=+1,off=h,lo=0,hi=h); h<0 -> med3(-p,h,0). 4 VALU -> 2.
//  - h2[j] folded into the 16-lane rotation reduce as h2j/16 (exact, pow2).
__global__ __launch_bounds__(1024)
__attribute__((amdgpu_waves_per_eu(4, 4)))
void plrnn_scan(const float* __restrict__ z0, const float* __restrict__ s,
                const float* __restrict__ A,  const float* __restrict__ W1,
                const float* __restrict__ W2, const float* __restrict__ h1,
                const float* __restrict__ h2, const float* __restrict__ C,
                float* __restrict__ out)
{
    const int tid = threadIdx.x;
    const int b   = blockIdx.x;
    const int h   = tid >> 2;            // phase-1 hidden unit (quad-owned)
    const int q   = tid & 3;             // which 16-wide quarter of the W1 dot
    const int j   = tid >> 4;            // phase-2 z output (row-owned), 0..63
    const int r4  = tid & 15;            // lane within row = 16-h slice

    __shared__ __align__(16) float z_sh[DZ];
    __shared__ __align__(16) float za_sh[320];        // skew: idx = h + (h>>4)*4
    __shared__ __align__(16) float s_sh[CHUNK * DS];  // 64 steps of s[t][b][0..15]

    // ---- loop-invariant weights (32 floats + C scalar) ----
    float4 w1v[4];    // W1[b][h][16q .. +16)  == 16 consecutive floats at 16*tid
    {
        const float4* p = (const float4*)(W1 + (size_t)b * DH * DZ) + 4 * tid;
        #pragma unroll
        for (int k = 0; k < 4; ++k) w1v[k] = p[k];
    }
    float4 w2v[4];    // W2[b][j][16*r4 .. +16) == 16 consecutive floats at 16*tid
    {
        const float4* p = (const float4*)(W2 + (size_t)b * DZ * DH) + 4 * tid;
        #pragma unroll
        for (int k = 0; k < 4; ++k) w2v[k] = p[k];
    }
    const float cj  = C[tid];             // C[j][r4]: DZ*DS == 1024 == blockDim

    // med3-relu constants: za = med3(sgn*p + off, lo, hi)
    const float h1r  = h1[h];
    const float rsgn = (h1r > 0.f) ?  1.f : -1.f;
    const float roff = (h1r > 0.f) ?  h1r :  0.f;
    const float rlo  = fminf(h1r, 0.f);
    const float rhi  = fmaxf(h1r, 0.f);

    const float Aj    = A[j];
    const float h2j16 = h2[j] * 0.0625f;  // h2[j]/16, folded into the reduce
    float zr = z0[b * DZ + j];            // z state for the row's j (replicated x16)

    if (tid < DZ) z_sh[tid] = z0[b * DZ + tid];

    // s prefetch: thread tid holds s[t0+srow][b][scol] for the NEXT chunk
    const int srow = tid >> 4, scol = tid & 15;
    float sreg = s[(size_t)min(srow, T_STEPS - 1) * NB * DS + (size_t)b * DS + scol];

    const int zi = h + ((h >> 4) << 2);   // skewed za_sh index for phase-1 store
    float* outp = out + (size_t)b * DZ + j;   // advanced by NB*DZ per step

    __syncthreads();

    for (int ci = 0; ci < NCHUNK; ++ci) {
        const int t0 = ci * CHUNK;
        s_sh[tid] = sreg;                 // visible after this step's barrier A
        {
            int tl = min(t0 + CHUNK + srow, T_STEPS - 1);
            sreg = s[(size_t)tl * NB * DS + (size_t)b * DS + scol];
        }

        #pragma unroll 4
        for (int tt = 0; tt < CHUNK; ++tt) {
            // ---- phase 1: Wz[h] = W1 row · z (LDS broadcast reads, free) ----
            const float4* z4 = (const float4*)(z_sh + 16 * q);
            float a0 = 0.f, a1 = 0.f, a2 = 0.f, a3 = 0.f;
            #pragma unroll
            for (int k = 0; k < 4; ++k) {
                float4 zv = z4[k];
                a0 = fmaf(w1v[k].x, zv.x, a0);
                a1 = fmaf(w1v[k].y, zv.y, a1);
                a2 = fmaf(w1v[k].z, zv.z, a2);
                a3 = fmaf(w1v[k].w, zv.w, a3);
            }
            float p1 = (a0 + a1) + (a2 + a3);
            p1 = dpp_add<0xB1>(p1);       // quad butterfly: += lane^1
            p1 = dpp_add<0x4E>(p1);       //                 += lane^2
            float za = __builtin_amdgcn_fmed3f(fmaf(rsgn, p1, roff), rlo, rhi);
            if (q == 0) za_sh[zi] = za;
            barrier_lgkm();               // A: za_sh (+ s_sh at chunk start) visible

            // ---- phase 2: row computes z_new[j] over full h ----
            const float4* q4 = (const float4*)(za_sh + 20 * r4);  // skewed 16-slice
            float sv = s_sh[tt * DS + r4];                        // this lane's s elem
            float p00 = fmaf(cj, sv, h2j16);                      // C·s + h2/16 folded
            float p01 = 0.f, p02 = 0.f, p03 = 0.f;
            #pragma unroll
            for (int k = 0; k < 4; ++k) {
                float4 v = q4[k];
                p00 = fmaf(w2v[k].x, v.x, p00);
                p01 = fmaf(w2v[k].y, v.y, p01);
                p02 = fmaf(w2v[k].z, v.z, p02);
                p03 = fmaf(w2v[k].w, v.w, p03);
            }
            float pa = (p00 + p01) + (p02 + p03);
            pa = row16_allsum(pa);        // VALU DPP rotation reduce (no LDS)

            // ---- epilogue: every lane of the row holds the full sum ----
            float zn = fmaf(Aj, zr, pa);
            zr = zn;
            const int t = t0 + tt;
            if (r4 == 0) {
                z_sh[j] = zn;
                if (t < T_STEPS) *outp = zn;
            }
            outp += NB * DZ;
            barrier_lgkm();               // B: z_sh update visible for next phase 1
        }
    }
}

extern "C" void kernel_launch(void* const* d_in, const int* in_sizes, int n_in,
                              void* d_out, int out_size, void* d_ws, size_t ws_size,
                              hipStream_t stream) {
    const float* z0p = (const float*)d_in[0];
    const float* sp  = (const float*)d_in[1];
    const float* Ap  = (const float*)d_in[2];
    const float* W1p = (const float*)d_in[3];
    const float* W2p = (const float*)d_in[4];
    const float* h1p = (const float*)d_in[5];
    const float* h2p = (const float*)d_in[6];
    const float* Cp  = (const float*)d_in[7];

    plrnn_scan<<<dim3(NB), dim3(1024), 0, stream>>>(z0p, sp, Ap, W1p, W2p, h1p, h2p, Cp,
                                                    (float*)d_out);
}

// Round 6
// 570.494 us; speedup vs baseline: 2.9730x; 1.0234x over previous
//
#include <hip/hip_runtime.h>

#define T_STEPS 1000
#define NB 256
#define DZ 64
#define DH 256
#define DS 16
#define CHUNK 64
#define NCHUNK 16   // 15 full chunks of 64 + last chunk of 40 = exactly 1000 steps

// LDS-only barrier: drains lgkmcnt (LDS ordering) but NOT vmcnt.
// Safe: global loads land in private regs; global stores are never read back.
__device__ __forceinline__ void barrier_lgkm() {
    asm volatile("s_waitcnt lgkmcnt(0)\n\ts_barrier" ::: "memory");
}

// VALU-pipe cross-lane add via DPP (fuses to v_add_f32_dpp).
// CTRL: 0xB1 = quad_perm[1,0,3,2] (xor1); 0x4E = quad_perm[2,3,0,1] (xor2);
//       0x121/0x122/0x124/0x128 = row_ror 1/2/4/8.
template<int CTRL>
__device__ __forceinline__ float dpp_add(float x) {
    int y = __builtin_amdgcn_update_dpp(0, __float_as_int(x), CTRL, 0xF, 0xF, true);
    return x + __int_as_float(y);
}
// Sum across the 16 lanes of a DPP row (every lane ends with the row total).
__device__ __forceinline__ float row16_allsum(float x) {
    x = dpp_add<0x128>(x);   // += ror8
    x = dpp_add<0x124>(x);   // += ror4
    x = dpp_add<0x122>(x);   // += ror2
    x = dpp_add<0x121>(x);   // += ror1
    return x;
}

// One block per trial b; 1024 threads = 16 waves = 4 waves/SIMD.
// Round-12: round-5 structure (measured best: 553us rocprof) with the step-count
// waste removed. Previously NCHUNK*CHUNK = 1024 steps ran for a 1000-step
// problem: 24 trailing steps (2.4% of the serial floor) were computed and
// discarded, and every step paid a t<T_STEPS compare+exec-mask. Now the last
// chunk runs 40 steps (15*64+40 = 1000 exactly) and the per-step bound check
// is gone (every computed step is stored). 64 and 40 both divide by the
// unroll-4, so no remainder path. Everything else identical to round-5:
//  - med3-relu (4 VALU -> 2), h2j/16 folded into the rotation reduce.
//  - 2 LDS-only barriers/step (proved irreducible: atomics 3x worse).
__global__ __launch_bounds__(1024)
__attribute__((amdgpu_waves_per_eu(4, 4)))
void plrnn_scan(const float* __restrict__ z0, const float* __restrict__ s,
                const float* __restrict__ A,  const float* __restrict__ W1,
                const float* __restrict__ W2, const float* __restrict__ h1,
                const float* __restrict__ h2, const float* __restrict__ C,
                float* __restrict__ out)
{
    const int tid = threadIdx.x;
    const int b   = blockIdx.x;
    const int h   = tid >> 2;            // phase-1 hidden unit (quad-owned)
    const int q   = tid & 3;             // which 16-wide quarter of the W1 dot
    const int j   = tid >> 4;            // phase-2 z output (row-owned), 0..63
    const int r4  = tid & 15;            // lane within row = 16-h slice

    __shared__ __align__(16) float z_sh[DZ];
    __shared__ __align__(16) float za_sh[320];        // skew: idx = h + (h>>4)*4
    __shared__ __align__(16) float s_sh[CHUNK * DS];  // 64 steps of s[t][b][0..15]

    // ---- loop-invariant weights (32 floats + C scalar) ----
    float4 w1v[4];    // W1[b][h][16q .. +16)  == 16 consecutive floats at 16*tid
    {
        const float4* p = (const float4*)(W1 + (size_t)b * DH * DZ) + 4 * tid;
        #pragma unroll
        for (int k = 0; k < 4; ++k) w1v[k] = p[k];
    }
    float4 w2v[4];    // W2[b][j][16*r4 .. +16) == 16 consecutive floats at 16*tid
    {
        const float4* p = (const float4*)(W2 + (size_t)b * DZ * DH) + 4 * tid;
        #pragma unroll
        for (int k = 0; k < 4; ++k) w2v[k] = p[k];
    }
    const float cj  = C[tid];             // C[j][r4]: DZ*DS == 1024 == blockDim

    // med3-relu constants: za = med3(sgn*p + off, lo, hi)
    const float h1r  = h1[h];
    const float rsgn = (h1r > 0.f) ?  1.f : -1.f;
    const float roff = (h1r > 0.f) ?  h1r :  0.f;
    const float rlo  = fminf(h1r, 0.f);
    const float rhi  = fmaxf(h1r, 0.f);

    const float Aj    = A[j];
    const float h2j16 = h2[j] * 0.0625f;  // h2[j]/16, folded into the reduce
    float zr = z0[b * DZ + j];            // z state for the row's j (replicated x16)

    if (tid < DZ) z_sh[tid] = z0[b * DZ + tid];

    // s prefetch: thread tid holds s[t0+srow][b][scol] for the NEXT chunk
    const int srow = tid >> 4, scol = tid & 15;
    float sreg = s[(size_t)min(srow, T_STEPS - 1) * NB * DS + (size_t)b * DS + scol];

    const int zi = h + ((h >> 4) << 2);   // skewed za_sh index for phase-1 store
    float* outp = out + (size_t)b * DZ + j;   // advanced by NB*DZ per step

    __syncthreads();

    for (int ci = 0; ci < NCHUNK; ++ci) {
        const int t0 = ci * CHUNK;
        const int nt = (ci == NCHUNK - 1) ? (T_STEPS - t0) : CHUNK;   // 64 or 40
        s_sh[tid] = sreg;                 // visible after this step's barrier A
        {
            int tl = min(t0 + CHUNK + srow, T_STEPS - 1);
            sreg = s[(size_t)tl * NB * DS + (size_t)b * DS + scol];
        }

        #pragma unroll 4
        for (int tt = 0; tt < nt; ++tt) {
            // ---- phase 1: Wz[h] = W1 row · z (LDS broadcast reads, free) ----
            const float4* z4 = (const float4*)(z_sh + 16 * q);
            float a0 = 0.f, a1 = 0.f, a2 = 0.f, a3 = 0.f;
            #pragma unroll
            for (int k = 0; k < 4; ++k) {
                float4 zv = z4[k];
                a0 = fmaf(w1v[k].x, zv.x, a0);
                a1 = fmaf(w1v[k].y, zv.y, a1);
                a2 = fmaf(w1v[k].z, zv.z, a2);
                a3 = fmaf(w1v[k].w, zv.w, a3);
            }
            float p1 = (a0 + a1) + (a2 + a3);
            p1 = dpp_add<0xB1>(p1);       // quad butterfly: += lane^1
            p1 = dpp_add<0x4E>(p1);       //                 += lane^2
            float za = __builtin_amdgcn_fmed3f(fmaf(rsgn, p1, roff), rlo, rhi);
            if (q == 0) za_sh[zi] = za;
            barrier_lgkm();               // A: za_sh (+ s_sh at chunk start) visible

            // ---- phase 2: row computes z_new[j] over full h ----
            const float4* q4 = (const float4*)(za_sh + 20 * r4);  // skewed 16-slice
            float sv = s_sh[tt * DS + r4];                        // this lane's s elem
            float p00 = fmaf(cj, sv, h2j16);                      // C·s + h2/16 folded
            float p01 = 0.f, p02 = 0.f, p03 = 0.f;
            #pragma unroll
            for (int k = 0; k < 4; ++k) {
                float4 v = q4[k];
                p00 = fmaf(w2v[k].x, v.x, p00);
                p01 = fmaf(w2v[k].y, v.y, p01);
                p02 = fmaf(w2v[k].z, v.z, p02);
                p03 = fmaf(w2v[k].w, v.w, p03);
            }
            float pa = (p00 + p01) + (p02 + p03);
            pa = row16_allsum(pa);        // VALU DPP rotation reduce (no LDS)

            // ---- epilogue: every lane of the row holds the full sum ----
            float zn = fmaf(Aj, zr, pa);
            zr = zn;
            if (r4 == 0) {
                z_sh[j] = zn;
                *outp = zn;               // every computed step is a real step now
            }
            outp += NB * DZ;
            barrier_lgkm();               // B: z_sh update visible for next phase 1
        }
    }
}

extern "C" void kernel_launch(void* const* d_in, const int* in_sizes, int n_in,
                              void* d_out, int out_size, void* d_ws, size_t ws_size,
                              hipStream_t stream) {
    const float* z0p = (const float*)d_in[0];
    const float* sp  = (const float*)d_in[1];
    const float* Ap  = (const float*)d_in[2];
    const float* W1p = (const float*)d_in[3];
    const float* W2p = (const float*)d_in[4];
    const float* h1p = (const float*)d_in[5];
    const float* h2p = (const float*)d_in[6];
    const float* Cp  = (const float*)d_in[7];

    plrnn_scan<<<dim3(NB), dim3(1024), 0, stream>>>(z0p, sp, Ap, W1p, W2p, h1p, h2p, Cp,
                                                    (float*)d_out);
}